// Round 15
// baseline (97.784 us; speedup 1.0000x reference)
//
#include <hip/hip_runtime.h>
#include <stdint.h>

typedef __attribute__((ext_vector_type(8))) short bf16x8;
typedef __attribute__((ext_vector_type(4))) float f32x4;

static constexpr int O1_ELEMS    = 512*3*3*128*128;   // 75497472 floats
static constexpr int WB2_FLOATS  = 1048576;           // 4 MB bf16 wb2[a][k][b]
static constexpr int P_FLOATS    = 512*9*128;         // 589824 per partial slice
static constexpr int NSEG        = 8;                 // a-split (16 a's per segment)
static constexpr size_t SCRATCH_BYTES = (size_t)WB2_FLOATS*4 + (size_t)NSEG*P_FLOATS*4; // 23068672
static constexpr int SKIP_TILES  = 352;               // fallback scratch head tiles
static constexpr int SKIP4       = SKIP_TILES * 4096; // 1441792 f32x4
static constexpr int TOTAL4      = O1_ELEMS / 4;      // 18874368 f32x4
static constexpr int A_END       = 2621440;           // K1 stream range end (40 MB)
static constexpr int B_END       = 11010048;          // K2 stream range end (+128 MB)

__device__ inline unsigned short f32_to_bf16(float f) {
    union { float f; uint32_t u; } v; v.f = f;
    uint32_t r = v.u + 0x7FFF + ((v.u >> 16) & 1);    // RNE
    return (unsigned short)(r >> 16);
}

__device__ inline bf16x8 bf16x8_from_f32(const float* p) {
    float4 v0 = *(const float4*)p;
    float4 v1 = *(const float4*)(p + 4);
    union { bf16x8 v; unsigned short s[8]; } u;
    u.s[0] = f32_to_bf16(v0.x); u.s[1] = f32_to_bf16(v0.y);
    u.s[2] = f32_to_bf16(v0.z); u.s[3] = f32_to_bf16(v0.w);
    u.s[4] = f32_to_bf16(v1.x); u.s[5] = f32_to_bf16(v1.y);
    u.s[6] = f32_to_bf16(v1.z); u.s[7] = f32_to_bf16(v1.w);
    return u.v;
}

// ---- fill-mimic stream: few blocks, long grid-stride runs, tight front ----
__device__ inline void stream_range(int lo4, int hi4, int stride, int tstart,
                                    const float* __restrict__ x,
                                    const float* __restrict__ y,
                                    float* __restrict__ out1) {
    const f32x4* y4 = (const f32x4*)y;
    f32x4* o4 = (f32x4*)out1;
    #pragma unroll 4
    for (int idx = lo4 + tstart; idx < hi4; idx += stride) {
        int n   = idx / 36864;
        int rem = idx - n * 36864;
        int ij  = rem >> 12;
        int r2  = rem & 4095;
        int aa  = r2 >> 5;
        int b4  = r2 & 31;
        int i = ij / 3, j = ij - 3 * i;
        float xs = x[(n * 3 + i) * 128 + aa];
        f32x4 yv = y4[(n * 3 + j) * 32 + b4];
        o4[idx] = yv * xs;
    }
}

// ---- tile writer (finish fallback only) ----
__device__ inline void write_tile(int tile, const float* __restrict__ x,
                                  const float* __restrict__ y,
                                  float* __restrict__ out1, int t) {
    const f32x4* y4 = (const f32x4*)y;
    f32x4* o4 = (f32x4*)out1;
    const int b4 = t & 31, a0 = t >> 5;
    int n  = tile / 9;
    int ij = tile - n * 9;
    int i  = ij / 3, j = ij - i * 3;
    f32x4 yv = y4[(n * 3 + j) * 32 + b4];
    const float* xrow = x + (n * 3 + i) * 128;
    f32x4* dst = o4 + (size_t)tile * 4096 + a0 * 32 + b4;
    #pragma unroll
    for (int p = 0; p < 16; ++p) {
        float xs = xrow[p * 8 + a0];
        f32x4 r = yv * xs;
        *dst = r;
        dst += 256;
    }
}

// ---- conv role: wb2[a][k][b] = bf16(w[a][b][k]) for one a ----
__device__ inline void conv_block(int a, int t, const float* __restrict__ w,
                                  unsigned short* __restrict__ wb2) {
    __shared__ unsigned short lt[128][132];
    const float4* src = (const float4*)(w + (size_t)a * 16384);
    #pragma unroll
    for (int it = 0; it < 16; ++it) {                  // 4096 float4 = 128x128 f32
        int fidx = it * 256 + t;
        float4 v = src[fidx];
        int b = fidx >> 5, k4 = fidx & 31;
        unsigned short* d = &lt[b][k4 * 4];
        d[0] = f32_to_bf16(v.x); d[1] = f32_to_bf16(v.y);
        d[2] = f32_to_bf16(v.z); d[3] = f32_to_bf16(v.w);
    }
    __syncthreads();
    const int k = t >> 1, bh = t & 1;
    uint4* dst = (uint4*)(wb2 + (size_t)a * 16384 + (size_t)k * 128 + bh * 64);
    #pragma unroll
    for (int i8 = 0; i8 < 8; ++i8) {
        uint32_t pk[4];
        #pragma unroll
        for (int q = 0; q < 4; ++q) {
            uint32_t lo = lt[bh * 64 + i8 * 8 + q * 2][k];
            uint32_t hi = lt[bh * 64 + i8 * 8 + q * 2 + 1][k];
            pk[q] = lo | (hi << 16);
        }
        uint4 vv = {pk[0], pk[1], pk[2], pk[3]};
        dst[i8] = vv;
    }
}

// ---- comp role (R12-validated): bid in [0,768) = 48 mt x 2 kt x 8 aseg ----
__device__ inline void comp_block(int bid, int tid, const float* __restrict__ x,
                                  const float* __restrict__ y,
                                  const unsigned short* __restrict__ wb2,
                                  float* __restrict__ partial) {
    __shared__ float xshc[16][3][32];      // [ac][i][m']  6 KB
    const int aseg = bid & 7;
    const int kt   = (bid >> 3) & 1;
    const int mt   = bid >> 4;             // 0..47
    const int l    = tid & 63;
    const int wv   = tid >> 6;
    const int l15  = l & 15, lg = l >> 4;

    bf16x8 afrag[2][4];
    #pragma unroll
    for (int Mt = 0; Mt < 2; ++Mt)
        #pragma unroll
        for (int ks = 0; ks < 4; ++ks)
            afrag[Mt][ks] = bf16x8_from_f32(
                y + (size_t)(mt * 32 + Mt * 16 + l15) * 128 + ks * 32 + lg * 8);

    #pragma unroll
    for (int p = 0; p < 6; ++p) {
        int e = tid + p * 256;
        int ac = e / 96, r = e - ac * 96, i = r >> 5, mm = r & 31;
        int n = (mt * 32 + mm) / 3;
        xshc[ac][i][mm] = x[n * 384 + i * 128 + aseg * 16 + ac];
    }
    __syncthreads();

    float acc2[3][2][4] = {};
    const unsigned short* wbase =
        wb2 + (size_t)(kt * 64 + wv * 16 + l15) * 128 + lg * 8;

    #pragma unroll 4
    for (int ac = 0; ac < 16; ++ac) {
        const int a = aseg * 16 + ac;
        const unsigned short* wp = wbase + (size_t)a * 16384;
        bf16x8 bf0 = *(const bf16x8*)(wp);
        bf16x8 bf1 = *(const bf16x8*)(wp + 32);
        bf16x8 bf2 = *(const bf16x8*)(wp + 64);
        bf16x8 bf3 = *(const bf16x8*)(wp + 96);

        f32x4 t0 = {0.f, 0.f, 0.f, 0.f}, t1 = {0.f, 0.f, 0.f, 0.f};
        t0 = __builtin_amdgcn_mfma_f32_16x16x32_bf16(afrag[0][0], bf0, t0, 0, 0, 0);
        t1 = __builtin_amdgcn_mfma_f32_16x16x32_bf16(afrag[1][0], bf0, t1, 0, 0, 0);
        t0 = __builtin_amdgcn_mfma_f32_16x16x32_bf16(afrag[0][1], bf1, t0, 0, 0, 0);
        t1 = __builtin_amdgcn_mfma_f32_16x16x32_bf16(afrag[1][1], bf1, t1, 0, 0, 0);
        t0 = __builtin_amdgcn_mfma_f32_16x16x32_bf16(afrag[0][2], bf2, t0, 0, 0, 0);
        t1 = __builtin_amdgcn_mfma_f32_16x16x32_bf16(afrag[1][2], bf2, t1, 0, 0, 0);
        t0 = __builtin_amdgcn_mfma_f32_16x16x32_bf16(afrag[0][3], bf3, t0, 0, 0, 0);
        t1 = __builtin_amdgcn_mfma_f32_16x16x32_bf16(afrag[1][3], bf3, t1, 0, 0, 0);

        #pragma unroll
        for (int i = 0; i < 3; ++i) {
            float4 xv0 = *(const float4*)&xshc[ac][i][lg * 4];
            float4 xv1 = *(const float4*)&xshc[ac][i][16 + lg * 4];
            acc2[i][0][0] += xv0.x * t0[0]; acc2[i][0][1] += xv0.y * t0[1];
            acc2[i][0][2] += xv0.z * t0[2]; acc2[i][0][3] += xv0.w * t0[3];
            acc2[i][1][0] += xv1.x * t1[0]; acc2[i][1][1] += xv1.y * t1[1];
            acc2[i][1][2] += xv1.z * t1[2]; acc2[i][1][3] += xv1.w * t1[3];
        }
    }

    float* pp = partial + (size_t)aseg * P_FLOATS;
    const int kcol = kt * 64 + wv * 16 + l15;
    #pragma unroll
    for (int i = 0; i < 3; ++i)
        #pragma unroll
        for (int Mt = 0; Mt < 2; ++Mt)
            #pragma unroll
            for (int r = 0; r < 4; ++r) {
                int m = mt * 32 + Mt * 16 + lg * 4 + r;
                int n = m / 3, j = m - 3 * n;
                pp[((size_t)(n * 3 + i) * 3 + j) * 128 + kcol] = acc2[i][Mt][r];
            }
}

// ---- K1: conv (0..127) || 128 long-run stream blocks over [lo4, A_END) ----
__global__ __launch_bounds__(256) void k1_kernel(const float* __restrict__ w,
                                                 const float* __restrict__ x,
                                                 const float* __restrict__ y,
                                                 unsigned short* __restrict__ wb2,
                                                 float* __restrict__ out1, int lo4) {
    const int b = (int)blockIdx.x;
    if (b < 128) { conv_block(b, (int)threadIdx.x, w, wb2); return; }
    stream_range(lo4, A_END, 128 * 256, (b - 128) * 256 + (int)threadIdx.x, x, y, out1);
}

// ---- K2: comp (0..767) || 256 long-run stream blocks over [A_END, B_END) ----
__global__ __launch_bounds__(256) void k2_kernel(const float* __restrict__ x,
                                                 const float* __restrict__ y,
                                                 const unsigned short* __restrict__ wb2,
                                                 float* __restrict__ partial,
                                                 float* __restrict__ out1) {
    const int b = (int)blockIdx.x;
    if (b < 768) { comp_block(b, (int)threadIdx.x, x, y, wb2, partial); return; }
    stream_range(A_END, B_END, 256 * 256, (b - 768) * 256 + (int)threadIdx.x, x, y, out1);
}

// ---- K3: reduce (all 2304) ; blocks 0..255 also stream [B_END, TOTAL4) ----
__global__ __launch_bounds__(256) void k3_kernel(const float* __restrict__ a_s,
                                                 const float* __restrict__ partial,
                                                 const float* __restrict__ x,
                                                 const float* __restrict__ y,
                                                 float* __restrict__ out1,
                                                 float* __restrict__ out2) {
    const int b = (int)blockIdx.x;
    const int e = b * 256 + (int)threadIdx.x;          // 2304*256 = P_FLOATS exact
    float s = 0.f;
    #pragma unroll
    for (int sg = 0; sg < NSEG; ++sg) s += partial[(size_t)sg * P_FLOATS + e];
    out2[e] = 0.75f * a_s[0] * s;
    if (b < 256)
        stream_range(B_END, TOTAL4, 256 * 256, b * 256 + (int)threadIdx.x, x, y, out1);
}

// ---- finish (fallback only): rewrite scratch-head tiles [0, SKIP_TILES) ----
__global__ __launch_bounds__(256) void finish_kernel(const float* __restrict__ x,
                                                     const float* __restrict__ y,
                                                     float* __restrict__ out1) {
    write_tile((int)blockIdx.x, x, y, out1, (int)threadIdx.x);
}

extern "C" void kernel_launch(void* const* d_in, const int* in_sizes, int n_in,
                              void* d_out, int out_size, void* d_ws, size_t ws_size,
                              hipStream_t stream) {
    const float* w  = (const float*)d_in[0];
    const float* as = (const float*)d_in[1];
    const float* x  = (const float*)d_in[2];
    const float* y  = (const float*)d_in[3];
    float* out1 = (float*)d_out;
    float* out2 = out1 + O1_ELEMS;

    const bool have_ws = (ws_size >= SCRATCH_BYTES);
    unsigned short* wb2;
    float* partial;
    int lo4;
    if (have_ws) {               // scratch in d_ws: stream covers [0, TOTAL4)
        wb2 = (unsigned short*)d_ws;
        partial = (float*)d_ws + WB2_FLOATS;
        lo4 = 0;
    } else {                     // scratch at out1 head (352 tiles), finish rewrites
        wb2 = (unsigned short*)out1;
        partial = out1 + WB2_FLOATS;
        lo4 = SKIP4;
    }

    k1_kernel<<<128 + 128, 256, 0, stream>>>(w, x, y, wb2, out1, lo4);
    k2_kernel<<<768 + 256, 256, 0, stream>>>(x, y, wb2, partial, out1);
    k3_kernel<<<2304, 256, 0, stream>>>(as, partial, x, y, out1, out2);
    if (!have_ws)
        finish_kernel<<<SKIP_TILES, 256, 0, stream>>>(x, y, out1);
}

// Round 16
// 85.769 us; speedup vs baseline: 1.1401x; 1.1401x over previous
//
#include <hip/hip_runtime.h>
#include <stdint.h>

typedef __attribute__((ext_vector_type(8))) short bf16x8;
typedef __attribute__((ext_vector_type(4))) float f32x4;

static constexpr int O1_ELEMS    = 512*3*3*128*128;   // 75497472 floats
static constexpr int WB2_FLOATS  = 1048576;           // 4 MB bf16 wb2[a][k][b]
static constexpr int P_FLOATS    = 512*9*128;         // 589824 per partial slice
static constexpr int NSEG        = 8;                 // a-split
static constexpr size_t SCRATCH_BYTES = (size_t)WB2_FLOATS*4 + (size_t)NSEG*P_FLOATS*4; // 23068672
static constexpr int NTILES      = 4608;              // 512*9 tiles (128x128 f32)
static constexpr int SKIP_TILES  = 352;               // 352*64KB = scratch bytes exactly
static constexpr int S1 = 1152, S2 = 1728;            // K1/K2 stream-tile counts

__device__ inline unsigned short f32_to_bf16(float f) {
    union { float f; uint32_t u; } v; v.f = f;
    uint32_t r = v.u + 0x7FFF + ((v.u >> 16) & 1);    // RNE
    return (unsigned short)(r >> 16);
}

__device__ inline bf16x8 bf16x8_from_f32(const float* p) {
    float4 v0 = *(const float4*)p;
    float4 v1 = *(const float4*)(p + 4);
    union { bf16x8 v; unsigned short s[8]; } u;
    u.s[0] = f32_to_bf16(v0.x); u.s[1] = f32_to_bf16(v0.y);
    u.s[2] = f32_to_bf16(v0.z); u.s[3] = f32_to_bf16(v0.w);
    u.s[4] = f32_to_bf16(v1.x); u.s[5] = f32_to_bf16(v1.y);
    u.s[6] = f32_to_bf16(v1.z); u.s[7] = f32_to_bf16(v1.w);
    return u.v;
}

// ---- one 128x128 out1 tile (256 thr), NONTEMPORAL stores (single change vs R12)
__device__ inline void write_tile(int tile, const float* __restrict__ x,
                                  const float* __restrict__ y,
                                  float* __restrict__ out1, int t) {
    const f32x4* y4 = (const f32x4*)y;
    f32x4* o4 = (f32x4*)out1;
    const int b4 = t & 31, a0 = t >> 5;               // col f4, row group 0..7
    int n  = tile / 9;
    int ij = tile - n * 9;
    int i  = ij / 3, j = ij - i * 3;
    f32x4 yv = y4[(n * 3 + j) * 32 + b4];
    const float* xrow = x + (n * 3 + i) * 128;
    f32x4* dst = o4 + (size_t)tile * 4096 + a0 * 32 + b4;
    #pragma unroll
    for (int p = 0; p < 16; ++p) {
        float xs = xrow[p * 8 + a0];                  // wave-broadcast load
        f32x4 r = yv * xs;
        __builtin_nontemporal_store(r, dst);          // bypass L2 write-allocate
        dst += 256;                                   // 8 rows * 32 f4
    }
}

// ---- conv role: wb2[a][k][b] = bf16(w[a][b][k]) for one a ----
__device__ inline void conv_block(int a, int t, const float* __restrict__ w,
                                  unsigned short* __restrict__ wb2) {
    __shared__ unsigned short lt[128][132];
    const float4* src = (const float4*)(w + (size_t)a * 16384);
    #pragma unroll
    for (int it = 0; it < 16; ++it) {                  // 4096 float4 = 128x128 f32
        int fidx = it * 256 + t;
        float4 v = src[fidx];
        int b = fidx >> 5, k4 = fidx & 31;
        unsigned short* d = &lt[b][k4 * 4];
        d[0] = f32_to_bf16(v.x); d[1] = f32_to_bf16(v.y);
        d[2] = f32_to_bf16(v.z); d[3] = f32_to_bf16(v.w);
    }
    __syncthreads();
    const int k = t >> 1, bh = t & 1;
    uint4* dst = (uint4*)(wb2 + (size_t)a * 16384 + (size_t)k * 128 + bh * 64);
    #pragma unroll
    for (int i8 = 0; i8 < 8; ++i8) {
        uint32_t pk[4];
        #pragma unroll
        for (int q = 0; q < 4; ++q) {
            uint32_t lo = lt[bh * 64 + i8 * 8 + q * 2][k];
            uint32_t hi = lt[bh * 64 + i8 * 8 + q * 2 + 1][k];
            pk[q] = lo | (hi << 16);
        }
        uint4 vv = {pk[0], pk[1], pk[2], pk[3]};
        dst[i8] = vv;
    }
}

// ---- comp role: partial[aseg][m,k] = sum_{a in seg} x[n,i,a] * t_a[m,k] ----
// bid in [0,768) = 48 mt x 2 kt x 8 aseg, 256 threads
__device__ inline void comp_block(int bid, int tid, const float* __restrict__ x,
                                  const float* __restrict__ y,
                                  const unsigned short* __restrict__ wb2,
                                  float* __restrict__ partial) {
    __shared__ float xshc[16][3][32];      // [ac][i][m']  6 KB
    const int aseg = bid & 7;
    const int kt   = (bid >> 3) & 1;
    const int mt   = bid >> 4;             // 0..47
    const int l    = tid & 63;
    const int wv   = tid >> 6;
    const int l15  = l & 15, lg = l >> 4;

    bf16x8 afrag[2][4];
    #pragma unroll
    for (int Mt = 0; Mt < 2; ++Mt)
        #pragma unroll
        for (int ks = 0; ks < 4; ++ks)
            afrag[Mt][ks] = bf16x8_from_f32(
                y + (size_t)(mt * 32 + Mt * 16 + l15) * 128 + ks * 32 + lg * 8);

    #pragma unroll
    for (int p = 0; p < 6; ++p) {
        int e = tid + p * 256;
        int ac = e / 96, r = e - ac * 96, i = r >> 5, mm = r & 31;
        int n = (mt * 32 + mm) / 3;
        xshc[ac][i][mm] = x[n * 384 + i * 128 + aseg * 16 + ac];
    }
    __syncthreads();

    float acc2[3][2][4] = {};
    const unsigned short* wbase =
        wb2 + (size_t)(kt * 64 + wv * 16 + l15) * 128 + lg * 8;

    #pragma unroll 4
    for (int ac = 0; ac < 16; ++ac) {
        const int a = aseg * 16 + ac;
        const unsigned short* wp = wbase + (size_t)a * 16384;
        bf16x8 bf0 = *(const bf16x8*)(wp);
        bf16x8 bf1 = *(const bf16x8*)(wp + 32);
        bf16x8 bf2 = *(const bf16x8*)(wp + 64);
        bf16x8 bf3 = *(const bf16x8*)(wp + 96);

        f32x4 t0 = {0.f, 0.f, 0.f, 0.f}, t1 = {0.f, 0.f, 0.f, 0.f};
        t0 = __builtin_amdgcn_mfma_f32_16x16x32_bf16(afrag[0][0], bf0, t0, 0, 0, 0);
        t1 = __builtin_amdgcn_mfma_f32_16x16x32_bf16(afrag[1][0], bf0, t1, 0, 0, 0);
        t0 = __builtin_amdgcn_mfma_f32_16x16x32_bf16(afrag[0][1], bf1, t0, 0, 0, 0);
        t1 = __builtin_amdgcn_mfma_f32_16x16x32_bf16(afrag[1][1], bf1, t1, 0, 0, 0);
        t0 = __builtin_amdgcn_mfma_f32_16x16x32_bf16(afrag[0][2], bf2, t0, 0, 0, 0);
        t1 = __builtin_amdgcn_mfma_f32_16x16x32_bf16(afrag[1][2], bf2, t1, 0, 0, 0);
        t0 = __builtin_amdgcn_mfma_f32_16x16x32_bf16(afrag[0][3], bf3, t0, 0, 0, 0);
        t1 = __builtin_amdgcn_mfma_f32_16x16x32_bf16(afrag[1][3], bf3, t1, 0, 0, 0);

        #pragma unroll
        for (int i = 0; i < 3; ++i) {
            float4 xv0 = *(const float4*)&xshc[ac][i][lg * 4];
            float4 xv1 = *(const float4*)&xshc[ac][i][16 + lg * 4];
            acc2[i][0][0] += xv0.x * t0[0]; acc2[i][0][1] += xv0.y * t0[1];
            acc2[i][0][2] += xv0.z * t0[2]; acc2[i][0][3] += xv0.w * t0[3];
            acc2[i][1][0] += xv1.x * t1[0]; acc2[i][1][1] += xv1.y * t1[1];
            acc2[i][1][2] += xv1.z * t1[2]; acc2[i][1][3] += xv1.w * t1[3];
        }
    }

    float* pp = partial + (size_t)aseg * P_FLOATS;
    const int kcol = kt * 64 + wv * 16 + l15;
    #pragma unroll
    for (int i = 0; i < 3; ++i)
        #pragma unroll
        for (int Mt = 0; Mt < 2; ++Mt)
            #pragma unroll
            for (int r = 0; r < 4; ++r) {
                int m = mt * 32 + Mt * 16 + lg * 4 + r;
                int n = m / 3, j = m - 3 * n;
                pp[((size_t)(n * 3 + i) * 3 + j) * 128 + kcol] = acc2[i][Mt][r];
            }
}

// ---- K1: conv (blocks 0..127) || stream tiles [t0, t0+S1) ----
__global__ __launch_bounds__(256) void k1_kernel(const float* __restrict__ w,
                                                 const float* __restrict__ x,
                                                 const float* __restrict__ y,
                                                 unsigned short* __restrict__ wb2,
                                                 float* __restrict__ out1, int t0) {
    const int b = (int)blockIdx.x;
    if (b < 128) { conv_block(b, (int)threadIdx.x, w, wb2); return; }
    write_tile(t0 + b - 128, x, y, out1, (int)threadIdx.x);
}

// ---- K2: comp (blocks 0..767) || stream tiles [t0, t0+S2) ----
__global__ __launch_bounds__(256) void k2_kernel(const float* __restrict__ x,
                                                 const float* __restrict__ y,
                                                 const unsigned short* __restrict__ wb2,
                                                 float* __restrict__ partial,
                                                 float* __restrict__ out1, int t0) {
    const int b = (int)blockIdx.x;
    if (b < 768) { comp_block(b, (int)threadIdx.x, x, y, wb2, partial); return; }
    write_tile(t0 + b - 768, x, y, out1, (int)threadIdx.x);
}

// ---- K3: reduce (all 2304 blocks) + stream tiles [t0, t0+ntiles) ----
__global__ __launch_bounds__(256) void k3_kernel(const float* __restrict__ a_s,
                                                 const float* __restrict__ partial,
                                                 const float* __restrict__ x,
                                                 const float* __restrict__ y,
                                                 float* __restrict__ out1,
                                                 float* __restrict__ out2,
                                                 int t0, int ntiles) {
    const int b = (int)blockIdx.x;
    const int e = b * 256 + (int)threadIdx.x;          // 2304*256 = P_FLOATS exact
    float s = 0.f;
    #pragma unroll
    for (int sg = 0; sg < NSEG; ++sg) s += partial[(size_t)sg * P_FLOATS + e];
    out2[e] = 0.75f * a_s[0] * s;
    if (b < ntiles)
        write_tile(t0 + b, x, y, out1, (int)threadIdx.x);
}

// ---- finish (fallback only): rewrite scratch-head tiles [0, SKIP_TILES) ----
__global__ __launch_bounds__(256) void finish_kernel(const float* __restrict__ x,
                                                     const float* __restrict__ y,
                                                     float* __restrict__ out1) {
    write_tile((int)blockIdx.x, x, y, out1, (int)threadIdx.x);
}

extern "C" void kernel_launch(void* const* d_in, const int* in_sizes, int n_in,
                              void* d_out, int out_size, void* d_ws, size_t ws_size,
                              hipStream_t stream) {
    const float* w  = (const float*)d_in[0];
    const float* as = (const float*)d_in[1];
    const float* x  = (const float*)d_in[2];
    const float* y  = (const float*)d_in[3];
    float* out1 = (float*)d_out;
    float* out2 = out1 + O1_ELEMS;

    const bool have_ws = (ws_size >= SCRATCH_BYTES);
    unsigned short* wb2;
    float* partial;
    int t0;
    if (have_ws) {               // scratch in d_ws: stream covers all 4608 tiles
        wb2 = (unsigned short*)d_ws;
        partial = (float*)d_ws + WB2_FLOATS;
        t0 = 0;
    } else {                     // scratch at out1 head (352 tiles), finish rewrites
        wb2 = (unsigned short*)out1;
        partial = out1 + WB2_FLOATS;
        t0 = SKIP_TILES;
    }
    const int s3 = NTILES - t0 - S1 - S2;   // ws: 1728; fallback: 1376

    k1_kernel<<<128 + S1, 256, 0, stream>>>(w, x, y, wb2, out1, t0);
    k2_kernel<<<768 + S2, 256, 0, stream>>>(x, y, wb2, partial, out1, t0 + S1);
    k3_kernel<<<2304, 256, 0, stream>>>(as, partial, x, y, out1, out2, t0 + S1 + S2, s3);
    if (!have_ws)
        finish_kernel<<<SKIP_TILES, 256, 0, stream>>>(x, y, out1);
}

// Round 17
// 72.535 us; speedup vs baseline: 1.3481x; 1.1824x over previous
//
#include <hip/hip_runtime.h>
#include <stdint.h>

typedef __attribute__((ext_vector_type(8))) short bf16x8;
typedef __attribute__((ext_vector_type(4))) float f32x4;

static constexpr int O1_ELEMS    = 512*3*3*128*128;   // 75497472 floats
static constexpr int WB2_FLOATS  = 1048576;           // 4 MB bf16 wb2[a][k][b]
static constexpr int P_FLOATS    = 512*9*128;         // 589824 per partial slice
static constexpr int NSEG        = 8;                 // a-split (16 a's per segment)
static constexpr size_t SCRATCH_BYTES = (size_t)WB2_FLOATS*4 + (size_t)NSEG*P_FLOATS*4; // 23068672
static constexpr int NTILES      = 4608;              // 512*9 tiles (128x128 f32)
static constexpr int SKIP_TILES  = 352;               // 352*64KB = scratch bytes exactly
static constexpr int S1 = 1152, S2 = 1728;            // K1/K2 stream-tile counts
static constexpr int NCOMP       = 384;               // 24 mt x 2 kt x 8 aseg

__device__ inline unsigned short f32_to_bf16(float f) {
    union { float f; uint32_t u; } v; v.f = f;
    uint32_t r = v.u + 0x7FFF + ((v.u >> 16) & 1);    // RNE
    return (unsigned short)(r >> 16);
}

__device__ inline bf16x8 bf16x8_from_f32(const float* p) {
    float4 v0 = *(const float4*)p;
    float4 v1 = *(const float4*)(p + 4);
    union { bf16x8 v; unsigned short s[8]; } u;
    u.s[0] = f32_to_bf16(v0.x); u.s[1] = f32_to_bf16(v0.y);
    u.s[2] = f32_to_bf16(v0.z); u.s[3] = f32_to_bf16(v0.w);
    u.s[4] = f32_to_bf16(v1.x); u.s[5] = f32_to_bf16(v1.y);
    u.s[6] = f32_to_bf16(v1.z); u.s[7] = f32_to_bf16(v1.w);
    return u.v;
}

// ---- one 128x128 out1 tile (256 thr), nontemporal stores (R16-validated) ----
__device__ inline void write_tile(int tile, const float* __restrict__ x,
                                  const float* __restrict__ y,
                                  float* __restrict__ out1, int t) {
    const f32x4* y4 = (const f32x4*)y;
    f32x4* o4 = (f32x4*)out1;
    const int b4 = t & 31, a0 = t >> 5;               // col f4, row group 0..7
    int n  = tile / 9;
    int ij = tile - n * 9;
    int i  = ij / 3, j = ij - i * 3;
    f32x4 yv = y4[(n * 3 + j) * 32 + b4];
    const float* xrow = x + (n * 3 + i) * 128;
    f32x4* dst = o4 + (size_t)tile * 4096 + a0 * 32 + b4;
    #pragma unroll
    for (int p = 0; p < 16; ++p) {
        float xs = xrow[p * 8 + a0];                  // wave-broadcast load
        f32x4 r = yv * xs;
        __builtin_nontemporal_store(r, dst);          // keep L2 for compute data
        dst += 256;                                   // 8 rows * 32 f4
    }
}

// ---- conv role: wb2[a][k][b] = bf16(w[a][b][k]) for one a ----
__device__ inline void conv_block(int a, int t, const float* __restrict__ w,
                                  unsigned short* __restrict__ wb2) {
    __shared__ unsigned short lt[128][132];
    const float4* src = (const float4*)(w + (size_t)a * 16384);
    #pragma unroll
    for (int it = 0; it < 16; ++it) {                  // 4096 float4 = 128x128 f32
        int fidx = it * 256 + t;
        float4 v = src[fidx];
        int b = fidx >> 5, k4 = fidx & 31;
        unsigned short* d = &lt[b][k4 * 4];
        d[0] = f32_to_bf16(v.x); d[1] = f32_to_bf16(v.y);
        d[2] = f32_to_bf16(v.z); d[3] = f32_to_bf16(v.w);
    }
    __syncthreads();
    const int k = t >> 1, bh = t & 1;
    uint4* dst = (uint4*)(wb2 + (size_t)a * 16384 + (size_t)k * 128 + bh * 64);
    #pragma unroll
    for (int i8 = 0; i8 < 8; ++i8) {
        uint32_t pk[4];
        #pragma unroll
        for (int q = 0; q < 4; ++q) {
            uint32_t lo = lt[bh * 64 + i8 * 8 + q * 2][k];
            uint32_t hi = lt[bh * 64 + i8 * 8 + q * 2 + 1][k];
            pk[q] = lo | (hi << 16);
        }
        uint4 vv = {pk[0], pk[1], pk[2], pk[3]};
        dst[i8] = vv;
    }
}

// ---- comp role, m-tile 64: bid in [0,384) = 24 mt x 2 kt x 8 aseg ----
// partial[aseg][m,k] = sum_{a in 16-wide seg} x[n,i,a] * t_a[m,k]
// wb2 re-read total: 384 blocks x 256 KB = 96 MB (half of R16's 192 MB)
__device__ inline void comp_block(int bid, int tid, const float* __restrict__ x,
                                  const float* __restrict__ y,
                                  const unsigned short* __restrict__ wb2,
                                  float* __restrict__ partial) {
    __shared__ float xshc[16][3][64];      // [ac][i][m']  12 KB
    const int aseg = bid & 7;
    const int kt   = (bid >> 3) & 1;
    const int mt   = bid >> 4;             // 0..23
    const int l    = tid & 63;
    const int wv   = tid >> 6;
    const int l15  = l & 15, lg = l >> 4;

    bf16x8 afrag[4][4];                    // [Mt][ks]: rows mt*64+Mt*16+l15
    #pragma unroll
    for (int Mt = 0; Mt < 4; ++Mt)
        #pragma unroll
        for (int ks = 0; ks < 4; ++ks)
            afrag[Mt][ks] = bf16x8_from_f32(
                y + (size_t)(mt * 64 + Mt * 16 + l15) * 128 + ks * 32 + lg * 8);

    #pragma unroll
    for (int p = 0; p < 12; ++p) {         // 3072 floats
        int e = tid + p * 256;
        int ac = e / 192, r = e - ac * 192, i = r >> 6, mm = r & 63;
        int n = (mt * 64 + mm) / 3;
        xshc[ac][i][mm] = x[n * 384 + i * 128 + aseg * 16 + ac];
    }
    __syncthreads();

    float acc2[3][4][4] = {};
    const unsigned short* wbase =
        wb2 + (size_t)(kt * 64 + wv * 16 + l15) * 128 + lg * 8;

    #pragma unroll 2
    for (int ac = 0; ac < 16; ++ac) {
        const int a = aseg * 16 + ac;
        const unsigned short* wp = wbase + (size_t)a * 16384;
        bf16x8 bf0 = *(const bf16x8*)(wp);
        bf16x8 bf1 = *(const bf16x8*)(wp + 32);
        bf16x8 bf2 = *(const bf16x8*)(wp + 64);
        bf16x8 bf3 = *(const bf16x8*)(wp + 96);

        f32x4 tt[4] = {{0.f,0.f,0.f,0.f},{0.f,0.f,0.f,0.f},
                       {0.f,0.f,0.f,0.f},{0.f,0.f,0.f,0.f}};
        #pragma unroll
        for (int Mt = 0; Mt < 4; ++Mt) {
            tt[Mt] = __builtin_amdgcn_mfma_f32_16x16x32_bf16(afrag[Mt][0], bf0, tt[Mt], 0, 0, 0);
            tt[Mt] = __builtin_amdgcn_mfma_f32_16x16x32_bf16(afrag[Mt][1], bf1, tt[Mt], 0, 0, 0);
            tt[Mt] = __builtin_amdgcn_mfma_f32_16x16x32_bf16(afrag[Mt][2], bf2, tt[Mt], 0, 0, 0);
            tt[Mt] = __builtin_amdgcn_mfma_f32_16x16x32_bf16(afrag[Mt][3], bf3, tt[Mt], 0, 0, 0);
        }

        #pragma unroll
        for (int i = 0; i < 3; ++i)
            #pragma unroll
            for (int Mt = 0; Mt < 4; ++Mt) {
                float4 xv = *(const float4*)&xshc[ac][i][Mt * 16 + lg * 4];
                acc2[i][Mt][0] += xv.x * tt[Mt][0];
                acc2[i][Mt][1] += xv.y * tt[Mt][1];
                acc2[i][Mt][2] += xv.z * tt[Mt][2];
                acc2[i][Mt][3] += xv.w * tt[Mt][3];
            }
    }

    float* pp = partial + (size_t)aseg * P_FLOATS;
    const int kcol = kt * 64 + wv * 16 + l15;
    #pragma unroll
    for (int i = 0; i < 3; ++i)
        #pragma unroll
        for (int Mt = 0; Mt < 4; ++Mt)
            #pragma unroll
            for (int r = 0; r < 4; ++r) {
                int m = mt * 64 + Mt * 16 + lg * 4 + r;
                int n = m / 3, j = m - 3 * n;
                pp[((size_t)(n * 3 + i) * 3 + j) * 128 + kcol] = acc2[i][Mt][r];
            }
}

// ---- K1: conv (blocks 0..127) || stream tiles [t0, t0+S1) ----
__global__ __launch_bounds__(256) void k1_kernel(const float* __restrict__ w,
                                                 const float* __restrict__ x,
                                                 const float* __restrict__ y,
                                                 unsigned short* __restrict__ wb2,
                                                 float* __restrict__ out1, int t0) {
    const int b = (int)blockIdx.x;
    if (b < 128) { conv_block(b, (int)threadIdx.x, w, wb2); return; }
    write_tile(t0 + b - 128, x, y, out1, (int)threadIdx.x);
}

// ---- K2: comp (blocks 0..NCOMP) || stream tiles [t0, t0+S2) ----
__global__ __launch_bounds__(256) void k2_kernel(const float* __restrict__ x,
                                                 const float* __restrict__ y,
                                                 const unsigned short* __restrict__ wb2,
                                                 float* __restrict__ partial,
                                                 float* __restrict__ out1, int t0) {
    const int b = (int)blockIdx.x;
    if (b < NCOMP) { comp_block(b, (int)threadIdx.x, x, y, wb2, partial); return; }
    write_tile(t0 + b - NCOMP, x, y, out1, (int)threadIdx.x);
}

// ---- K3: reduce (all 2304 blocks) + stream tiles [t0, t0+ntiles) ----
__global__ __launch_bounds__(256) void k3_kernel(const float* __restrict__ a_s,
                                                 const float* __restrict__ partial,
                                                 const float* __restrict__ x,
                                                 const float* __restrict__ y,
                                                 float* __restrict__ out1,
                                                 float* __restrict__ out2,
                                                 int t0, int ntiles) {
    const int b = (int)blockIdx.x;
    const int e = b * 256 + (int)threadIdx.x;          // 2304*256 = P_FLOATS exact
    float s = 0.f;
    #pragma unroll
    for (int sg = 0; sg < NSEG; ++sg) s += partial[(size_t)sg * P_FLOATS + e];
    out2[e] = 0.75f * a_s[0] * s;
    if (b < ntiles)
        write_tile(t0 + b, x, y, out1, (int)threadIdx.x);
}

// ---- finish (fallback only): rewrite scratch-head tiles [0, SKIP_TILES) ----
__global__ __launch_bounds__(256) void finish_kernel(const float* __restrict__ x,
                                                     const float* __restrict__ y,
                                                     float* __restrict__ out1) {
    write_tile((int)blockIdx.x, x, y, out1, (int)threadIdx.x);
}

extern "C" void kernel_launch(void* const* d_in, const int* in_sizes, int n_in,
                              void* d_out, int out_size, void* d_ws, size_t ws_size,
                              hipStream_t stream) {
    const float* w  = (const float*)d_in[0];
    const float* as = (const float*)d_in[1];
    const float* x  = (const float*)d_in[2];
    const float* y  = (const float*)d_in[3];
    float* out1 = (float*)d_out;
    float* out2 = out1 + O1_ELEMS;

    const bool have_ws = (ws_size >= SCRATCH_BYTES);
    unsigned short* wb2;
    float* partial;
    int t0;
    if (have_ws) {               // scratch in d_ws: stream covers all 4608 tiles
        wb2 = (unsigned short*)d_ws;
        partial = (float*)d_ws + WB2_FLOATS;
        t0 = 0;
    } else {                     // scratch at out1 head (352 tiles), finish rewrites
        wb2 = (unsigned short*)out1;
        partial = out1 + WB2_FLOATS;
        t0 = SKIP_TILES;
    }
    const int s3 = NTILES - t0 - S1 - S2;   // ws: 1728; fallback: 1376

    k1_kernel<<<128 + S1, 256, 0, stream>>>(w, x, y, wb2, out1, t0);
    k2_kernel<<<NCOMP + S2, 256, 0, stream>>>(x, y, wb2, partial, out1, t0 + S1);
    k3_kernel<<<2304, 256, 0, stream>>>(as, partial, x, y, out1, out2, t0 + S1 + S2, s3);
    if (!have_ws)
        finish_kernel<<<SKIP_TILES, 256, 0, stream>>>(x, y, out1);
}